// Round 10
// baseline (264.724 us; speedup 1.0000x reference)
//
#include <hip/hip_runtime.h>

typedef __attribute__((ext_vector_type(8))) short bf16x8;
typedef __attribute__((ext_vector_type(4))) float f32x4;
typedef unsigned short u16;
typedef unsigned int u32;

#define T_SEQ 2048
#define C_DIM 1024
#define NH 16
#define HD 64
#define BATCH 2

__device__ __forceinline__ u16 f2bf(float f) {
    union { float f; u32 u; } v; v.f = f;
    u32 u = v.u;
    u32 r = (u + 0x7FFFu + ((u >> 16) & 1u)) >> 16;
    return (u16)r;
}

__device__ __forceinline__ float fexp2(float x) { return __builtin_amdgcn_exp2f(x); }

__device__ __forceinline__ float bflo(u32 u) {   // low bf16 -> f32
    union { u32 u; float f; } v; v.u = u << 16; return v.f;
}
__device__ __forceinline__ float bfhi(u32 u) {   // high bf16 -> f32
    union { u32 u; float f; } v; v.u = u & 0xFFFF0000u; return v.f;
}

// async global->LDS, 16B per lane; LDS dest is wave-uniform base + lane*16
__device__ __forceinline__ void gld_lds16(const void* g, void* l) {
    __builtin_amdgcn_global_load_lds(
        (const __attribute__((address_space(1))) void*)g,
        (__attribute__((address_space(3))) void*)l, 16, 0, 0);
}

// ---------------------------------------------------------------------------
// Transpose 4 weight matrices [C,C] f32 -> [C,C] bf16 (WT[n][k] = W[k][n])
// ---------------------------------------------------------------------------
__global__ __launch_bounds__(256) void transpose_to_bf16(
    const float* __restrict__ W0, const float* __restrict__ W1,
    const float* __restrict__ W2, const float* __restrict__ W3,
    u16* __restrict__ O0, u16* __restrict__ O1,
    u16* __restrict__ O2, u16* __restrict__ O3)
{
    __shared__ float tile[32][33];
    const float* W = blockIdx.z == 0 ? W0 : blockIdx.z == 1 ? W1 : blockIdx.z == 2 ? W2 : W3;
    u16* O = blockIdx.z == 0 ? O0 : blockIdx.z == 1 ? O1 : blockIdx.z == 2 ? O2 : O3;
    const int tx = threadIdx.x, ty = threadIdx.y;
    const int bx = blockIdx.x * 32, by = blockIdx.y * 32;
#pragma unroll
    for (int i = 0; i < 4; ++i)
        tile[ty + i * 8][tx] = W[(size_t)(by + ty + i * 8) * C_DIM + bx + tx];
    __syncthreads();
#pragma unroll
    for (int i = 0; i < 4; ++i)
        O[(size_t)(bx + ty + i * 8) * C_DIM + by + tx] = f2bf(tile[tx][ty + i * 8]);
}

// ---------------------------------------------------------------------------
// GEMM: Y[M,N] = X[M,K] @ W[K,N] + bias, WT[N,K] pre-transposed bf16.
// 64x128 (MxN) tile, BK=64, 4 waves (each 64 rows x 32 cols, acc 4x2).
// DOUBLE-BUFFERED LDS, one barrier per K-step: stage(t+1) issued before
// compute(t); __syncthreads' implicit vmcnt(0)/lgkmcnt(0) drains both.
// Grid (N/128, M/64, nz); blockIdx.z selects pointer set (q/k fusion).
// OMODE: 0 = bf16 row-major, 1 = f32 row-major, 2 = bf16 per-head V^T
// ---------------------------------------------------------------------------
template<bool XF32, int OMODE>
__global__ __launch_bounds__(256) void gemm_bt(
    const void* __restrict__ X0_, const void* __restrict__ X1_,
    const u16* __restrict__ W0T, const u16* __restrict__ W1T,
    const float* __restrict__ b0_, const float* __restrict__ b1_,
    void* __restrict__ Y0_, void* __restrict__ Y1_,
    int M, int N, int K)
{
    __shared__ u16 As[2][64 * 64];     // 16 KB
    __shared__ u16 Bs[2][128 * 64];    // 32 KB
    const int tid = threadIdx.x;
    const int w = tid >> 6, l = tid & 63;
    const int lr = l & 15, lg = l >> 4;
    const int z = blockIdx.z;
    const void* Xv = z ? X1_ : X0_;
    const u16* WT = z ? W1T : W0T;
    const float* bias = z ? b1_ : b0_;
    void* Yv = z ? Y1_ : Y0_;
    const int m0 = blockIdx.y * 64, n0 = blockIdx.x * 128;
    const int grow8 = l >> 3;          // 0..7  (8 rows per gld, 64 cols)
    const int gcol8 = (l & 7) * 8;     // u16 col
    const int rowA = tid >> 2, cgA = tid & 3;   // f32 A staging
    f32x4 acc[4][2] = {};

    // stage B tile (128 x 64) for K-offset k0 into buffer buf: 4 gld per wave
    auto stageB = [&](int k0, int buf) {
#pragma unroll
        for (int i = 0; i < 4; ++i)
            gld_lds16(WT + (size_t)(n0 + w * 32 + i * 8 + grow8) * K + k0 + gcol8,
                      &Bs[buf][(w * 32 + i * 8) * 64]);
    };
    // stage A tile (64 x 64) bf16 path: 2 gld per wave
    auto stageAb = [&](int k0, int buf) {
#pragma unroll
        for (int i = 0; i < 2; ++i)
            gld_lds16((const u16*)Xv + (size_t)(m0 + w * 16 + i * 8 + grow8) * K + k0 + gcol8,
                      &As[buf][(w * 16 + i * 8) * 64]);
    };

    // ---- prologue: stage tile 0 into buf 0 ----
    if (XF32) {
        const float* g = (const float*)Xv + (size_t)(m0 + rowA) * K + cgA * 16;
        float4 a0 = *(const float4*)g;
        float4 a1 = *(const float4*)(g + 4);
        float4 a2 = *(const float4*)(g + 8);
        float4 a3 = *(const float4*)(g + 12);
        union { u16 h[8]; uint4 q; } p0, p1;
        p0.h[0] = f2bf(a0.x); p0.h[1] = f2bf(a0.y); p0.h[2] = f2bf(a0.z); p0.h[3] = f2bf(a0.w);
        p0.h[4] = f2bf(a1.x); p0.h[5] = f2bf(a1.y); p0.h[6] = f2bf(a1.z); p0.h[7] = f2bf(a1.w);
        p1.h[0] = f2bf(a2.x); p1.h[1] = f2bf(a2.y); p1.h[2] = f2bf(a2.z); p1.h[3] = f2bf(a2.w);
        p1.h[4] = f2bf(a3.x); p1.h[5] = f2bf(a3.y); p1.h[6] = f2bf(a3.z); p1.h[7] = f2bf(a3.w);
        *(uint4*)&As[0][rowA * 64 + cgA * 16] = p0.q;
        *(uint4*)&As[0][rowA * 64 + cgA * 16 + 8] = p1.q;
    } else {
        stageAb(0, 0);
    }
    stageB(0, 0);
    __syncthreads();

    int cur = 0;
    for (int k0 = 0; k0 < K; k0 += 64) {
        const bool has_next = (k0 + 64 < K);
        // ---- issue next-tile staging first (overlaps with MFMA below) ----
        float4 a0, a1, a2, a3;
        if (has_next) {
            if (XF32) {
                const float* g = (const float*)Xv + (size_t)(m0 + rowA) * K + k0 + 64 + cgA * 16;
                a0 = *(const float4*)g;
                a1 = *(const float4*)(g + 4);
                a2 = *(const float4*)(g + 8);
                a3 = *(const float4*)(g + 12);
            } else {
                stageAb(k0 + 64, cur ^ 1);
            }
            stageB(k0 + 64, cur ^ 1);
        }
        // ---- compute on current buffer ----
#pragma unroll
        for (int h = 0; h < 2; ++h) {
            bf16x8 af[4], bfr[2];
#pragma unroll
            for (int i = 0; i < 4; ++i)
                af[i] = *(const bf16x8*)&As[cur][(i * 16 + lr) * 64 + h * 32 + lg * 8];
#pragma unroll
            for (int j = 0; j < 2; ++j)
                bfr[j] = *(const bf16x8*)&Bs[cur][(w * 32 + j * 16 + lr) * 64 + h * 32 + lg * 8];
#pragma unroll
            for (int i = 0; i < 4; ++i)
#pragma unroll
                for (int j = 0; j < 2; ++j)
                    acc[i][j] = __builtin_amdgcn_mfma_f32_16x16x32_bf16(af[i], bfr[j], acc[i][j], 0, 0, 0);
        }
        // ---- f32 A: convert + LDS write for next tile ----
        if (XF32 && has_next) {
            union { u16 h[8]; uint4 q; } p0, p1;
            p0.h[0] = f2bf(a0.x); p0.h[1] = f2bf(a0.y); p0.h[2] = f2bf(a0.z); p0.h[3] = f2bf(a0.w);
            p0.h[4] = f2bf(a1.x); p0.h[5] = f2bf(a1.y); p0.h[6] = f2bf(a1.z); p0.h[7] = f2bf(a1.w);
            p1.h[0] = f2bf(a2.x); p1.h[1] = f2bf(a2.y); p1.h[2] = f2bf(a2.z); p1.h[3] = f2bf(a2.w);
            p1.h[4] = f2bf(a3.x); p1.h[5] = f2bf(a3.y); p1.h[6] = f2bf(a3.z); p1.h[7] = f2bf(a3.w);
            *(uint4*)&As[cur ^ 1][rowA * 64 + cgA * 16] = p0.q;
            *(uint4*)&As[cur ^ 1][rowA * 64 + cgA * 16 + 8] = p1.q;
        }
        __syncthreads();   // implicit vmcnt(0)+lgkmcnt(0): next buffer complete
        cur ^= 1;
    }

#pragma unroll
    for (int i = 0; i < 4; ++i) {
        const int rowb = m0 + i * 16 + lg * 4;
#pragma unroll
        for (int j = 0; j < 2; ++j) {
            const int col = n0 + w * 32 + j * 16 + lr;
            const float bv = bias[col];
            if (OMODE == 2) {
                union { u16 h[4]; uint2 q; } pk;
#pragma unroll
                for (int r = 0; r < 4; ++r) pk.h[r] = f2bf(acc[i][j][r] + bv);
                const int bb = rowb >> 11, tt = rowb & 2047;
                const int hh = col >> 6, dd = col & 63;
                u16* dst = (u16*)Yv + ((size_t)((bb * NH + hh) * HD + dd)) * T_SEQ + tt;
                *(uint2*)dst = pk.q;
            } else {
#pragma unroll
                for (int r = 0; r < 4; ++r) {
                    const float v = acc[i][j][r] + bv;
                    if (OMODE == 1)
                        ((float*)Yv)[(size_t)(rowb + r) * N + col] = v;
                    else
                        ((u16*)Yv)[(size_t)(rowb + r) * N + col] = f2bf(v);
                }
            }
        }
    }
}

// ---------------------------------------------------------------------------
// Causal attention. Block = (b, h, 16 q-rows), 8 waves (512 thr) -> 2 blocks
// resident per CU (independent barrier domains overlap).
// kv split in 32-wide tiles, up to 8 per wave (ti = w + 8*j).
// Phase 0: zero-fill upper region (independent; overlaps phase A).
// Phase A: S once; per tile cache mt_j (lane max), S_j (lane sumexp), and
//          e = exp2(s - mt_j) packed as 2xbf16 per u32 (16 VGPR for 8 tiles).
// Phase B: p = e * exp2(mt_j - mf)/lf; nontemporal P stores; shfl-transpose
//          into PV A-frag; setprio around PV MFMA.
// Grid flattened + XCD-swizzled so each XCD owns 4 consecutive heads.
// ---------------------------------------------------------------------------
#define PV_QS 67                 // float stride per q-row in pvbuf
#define PV_WS (16 * PV_QS + 8)   // float stride per wave block

__global__ __launch_bounds__(512, 4) void attn_kernel(
    const u16* __restrict__ qp, const u16* __restrict__ kp,
    const u16* __restrict__ vt, u16* __restrict__ ctx,
    float* __restrict__ attn)
{
    __shared__ float statm[8][16], statl[8][16];
    __shared__ float pvbuf[8 * PV_WS];

    const int tid = threadIdx.x;
    const int w = tid >> 6, l = tid & 63;
    const int lr = l & 15, lg = l >> 4;

    // XCD-aware bijective swizzle: 4096 blocks, 8 XCDs, 512 blocks each.
    const int wgid = (blockIdx.x & 7) * 512 + (blockIdx.x >> 3);
    const int b = wgid >> 11;
    const int h = (wgid >> 7) & 15;
    const int strip = 127 - (wgid & 127);   // heavy-first within XCD chunk
    const int q0 = strip * 16;

    const size_t bh_off = (size_t)b * T_SEQ * C_DIM + h * HD;
    const u16* qb = qp + bh_off;
    const u16* kb = kp + bh_off;
    const u16* vtb = vt + ((size_t)(b * NH + h) * HD) * T_SEQ;
    float* ab = attn + (size_t)(b * NH + h) * T_SEQ * T_SEQ;

    const float SC = 0.125f * 1.44269504088896f;   // 1/sqrt(64) * log2(e)
    const float MNEG = -1e30f;

    const int qrow = q0 + lr;
    const int n32 = (q0 + 47) >> 5;       // 32-wide kv tiles (kv_end = q0+16)

    // ---- phase 0: zero-fill upper region (independent, overlaps A) ----
    {
        const int zs = n32 * 32;
        const int row = tid >> 5;           // 0..15
        const int c0 = (tid & 31) * 4;
        float* zr = ab + (size_t)(q0 + row) * T_SEQ;
        const f32x4 z4 = { 0.f, 0.f, 0.f, 0.f };
        for (int c = zs + c0; c < T_SEQ; c += 128)
            __builtin_nontemporal_store(z4, (f32x4*)(zr + c));
    }

    const bf16x8 aq0 = *(const bf16x8*)(qb + (size_t)(q0 + lr) * C_DIM + lg * 8);
    const bf16x8 aq1 = *(const bf16x8*)(qb + (size_t)(q0 + lr) * C_DIM + 32 + lg * 8);

    // ---- phase A: S once; cache mt_j, S_j, packed e per tile ----
    u32 ec[8][2];     // e packed 2xbf16: [j][t2] r0,r1
    u32 ec2[8][2];    // [j][t2] r2,r3
    float mtj[8], Sj[8];
    float ml = MNEG;
#pragma unroll
    for (int j = 0; j < 8; ++j) {
        const int ti = w + 8 * j;
        if (ti < n32) {
            const int kvb = ti * 32;
            const u16* kr0 = kb + (size_t)(kvb + lr) * C_DIM;
            const u16* kr1 = kb + (size_t)(kvb + 16 + lr) * C_DIM;
            const bf16x8 k00 = *(const bf16x8*)(kr0 + lg * 8);
            const bf16x8 k01 = *(const bf16x8*)(kr0 + 32 + lg * 8);
            const bf16x8 k10 = *(const bf16x8*)(kr1 + lg * 8);
            const bf16x8 k11 = *(const bf16x8*)(kr1 + 32 + lg * 8);
            f32x4 s[2] = {};
            s[0] = __builtin_amdgcn_mfma_f32_16x16x32_bf16(k00, aq0, s[0], 0, 0, 0);
            s[0] = __builtin_amdgcn_mfma_f32_16x16x32_bf16(k01, aq1, s[0], 0, 0, 0);
            s[1] = __builtin_amdgcn_mfma_f32_16x16x32_bf16(k10, aq0, s[1], 0, 0, 0);
            s[1] = __builtin_amdgcn_mfma_f32_16x16x32_bf16(k11, aq1, s[1], 0, 0, 0);
            float sv[2][4];
            float mt = MNEG;
#pragma unroll
            for (int t = 0; t < 2; ++t)
#pragma unroll
                for (int r = 0; r < 4; ++r) {
                    float v = s[t][r] * SC;
                    if (kvb + 16 * t + 4 * lg + r > qrow) v = MNEG;
                    sv[t][r] = v;
                    mt = fmaxf(mt, v);
                }
            mtj[j] = mt;
            float ss = 0.f;
            float e[2][4];
#pragma unroll
            for (int t = 0; t < 2; ++t)
#pragma unroll
                for (int r = 0; r < 4; ++r) {
                    e[t][r] = fexp2(sv[t][r] - mt);
                    ss += e[t][r];
                }
            Sj[j] = ss;
#pragma unroll
            for (int t = 0; t < 2; ++t) {
                ec[j][t]  = (u32)f2bf(e[t][0]) | ((u32)f2bf(e[t][1]) << 16);
                ec2[j][t] = (u32)f2bf(e[t][2]) | ((u32)f2bf(e[t][3]) << 16);
            }
            ml = fmaxf(ml, mt);
        } else {
            mtj[j] = MNEG; Sj[j] = 0.f;
            ec[j][0] = ec[j][1] = ec2[j][0] = ec2[j][1] = 0;
        }
    }
    float ll = 0.f;
#pragma unroll
    for (int j = 0; j < 8; ++j) ll += Sj[j] * fexp2(mtj[j] - ml);
    // cross-lane (lg) combine
#pragma unroll
    for (int d = 16; d <= 32; d <<= 1) {
        const float mo = __shfl_xor(ml, d);
        const float lo = __shfl_xor(ll, d);
        const float mn = fmaxf(ml, mo);
        ll = ll * fexp2(ml - mn) + lo * fexp2(mo - mn);
        ml = mn;
    }
    if (l < 16) { statm[w][lr] = ml; statl[w][lr] = ll; }
    __syncthreads();

    float mf = MNEG;
#pragma unroll
    for (int ww = 0; ww < 8; ++ww) mf = fmaxf(mf, statm[ww][lr]);
    float lf = 0.f;
#pragma unroll
    for (int ww = 0; ww < 8; ++ww) lf += statl[ww][lr] * fexp2(statm[ww][lr] - mf);
    const float rlf = 1.f / lf;

    // ---- phase B: P stores + PV from cached e ----
    f32x4 cacc[4] = {};
#pragma unroll
    for (int j = 0; j < 8; ++j) {
        const int ti = w + 8 * j;
        if (ti < n32) {
            const int kvb = ti * 32;
            bf16x8 vf[4];
#pragma unroll
            for (int dt = 0; dt < 4; ++dt)
                vf[dt] = *(const bf16x8*)(vtb + (size_t)(dt * 16 + lr) * T_SEQ + kvb + lg * 8);
            const float scale = fexp2(mtj[j] - mf) * rlf;
            u32 pw[2][2];
#pragma unroll
            for (int t2 = 0; t2 < 2; ++t2) {
                float p[4];
                p[0] = bflo(ec[j][t2]) * scale;
                p[1] = bfhi(ec[j][t2]) * scale;
                p[2] = bflo(ec2[j][t2]) * scale;
                p[3] = bfhi(ec2[j][t2]) * scale;
                f32x4 pv4 = { p[0], p[1], p[2], p[3] };
                __builtin_nontemporal_store(pv4,
                    (f32x4*)(ab + (size_t)qrow * T_SEQ + kvb + 16 * t2 + 4 * lg));
                pw[t2][0] = (u32)f2bf(p[0]) | ((u32)f2bf(p[1]) << 16);
                pw[t2][1] = (u32)f2bf(p[2]) | ((u32)f2bf(p[3]) << 16);
            }
            // shuffle-transpose: C-layout (kv in lg-groups of 4) -> A-frag (kv=8*lg+jj)
            const int bl = lr + ((lg & 1) << 5);
            const u32 a0 = (u32)__shfl((int)pw[0][0], bl);
            const u32 a1 = (u32)__shfl((int)pw[0][1], bl);
            const u32 a2 = (u32)__shfl((int)pw[0][0], bl + 16);
            const u32 a3 = (u32)__shfl((int)pw[0][1], bl + 16);
            const u32 b0 = (u32)__shfl((int)pw[1][0], bl);
            const u32 b1 = (u32)__shfl((int)pw[1][1], bl);
            const u32 b2 = (u32)__shfl((int)pw[1][0], bl + 16);
            const u32 b3 = (u32)__shfl((int)pw[1][1], bl + 16);
            const bool hi2 = lg >= 2;
            union { u32 ww[4]; bf16x8 v; } pa;
            pa.ww[0] = hi2 ? b0 : a0;
            pa.ww[1] = hi2 ? b1 : a1;
            pa.ww[2] = hi2 ? b2 : a2;
            pa.ww[3] = hi2 ? b3 : a3;
            __builtin_amdgcn_s_setprio(1);
#pragma unroll
            for (int dt = 0; dt < 4; ++dt)
                cacc[dt] = __builtin_amdgcn_mfma_f32_16x16x32_bf16(pa.v, vf[dt], cacc[dt], 0, 0, 0);
            __builtin_amdgcn_s_setprio(0);
        }
    }

    // dump PV partials (cacc[dt][r] = ctx[q=4*lg+r][d=dt*16+lr])
    {
        float* pwv = pvbuf + w * PV_WS;
#pragma unroll
        for (int dt = 0; dt < 4; ++dt)
#pragma unroll
            for (int r = 0; r < 4; ++r)
                pwv[(4 * lg + r) * PV_QS + dt * 16 + lr] = cacc[dt][r];
    }
    __syncthreads();

    // reduce PV across 8 waves + write ctx (bf16): 1024 elems, 512 thr x 2
    {
        const int qq = tid >> 5;            // 0..15
        const int d0 = (tid & 31) * 2;      // 0..62
        float s0 = 0.f, s1 = 0.f;
#pragma unroll
        for (int ww = 0; ww < 8; ++ww) {
            const float* pwv = pvbuf + ww * PV_WS + qq * PV_QS;
            s0 += pwv[d0];
            s1 += pwv[d0 + 1];
        }
        union { u16 hh[2]; u32 u; } pk;
        pk.hh[0] = f2bf(s0); pk.hh[1] = f2bf(s1);
        u16* cb = ctx + bh_off;
        *(u32*)(cb + (size_t)(q0 + qq) * C_DIM + d0) = pk.u;
    }
}

// ---------------------------------------------------------------------------
extern "C" void kernel_launch(void* const* d_in, const int* in_sizes, int n_in,
                              void* d_out, int out_size, void* d_ws, size_t ws_size,
                              hipStream_t stream)
{
    const float* q  = (const float*)d_in[0];
    const float* k  = (const float*)d_in[1];
    const float* Wq = (const float*)d_in[2];
    const float* bq = (const float*)d_in[3];
    const float* Wk = (const float*)d_in[4];
    const float* bk = (const float*)d_in[5];
    const float* Wv = (const float*)d_in[6];
    const float* bv = (const float*)d_in[7];
    const float* Wo = (const float*)d_in[8];
    const float* bo = (const float*)d_in[9];
    (void)in_sizes; (void)n_in; (void)out_size; (void)ws_size;

    float* out = (float*)d_out;
    float* attn = out + (size_t)BATCH * T_SEQ * C_DIM;

    const size_t MC = (size_t)BATCH * T_SEQ * C_DIM;   // 4,194,304 elems
    u16* qp  = (u16*)d_ws;
    u16* kp  = qp + MC;
    u16* vt  = kp + MC;          // V^T: [B][H][D][T]
    u16* ctx = vt + MC;
    u16* WqT = ctx + MC;
    u16* WkT = WqT + (size_t)C_DIM * C_DIM;
    u16* WvT = WkT + (size_t)C_DIM * C_DIM;
    u16* WoT = WvT + (size_t)C_DIM * C_DIM;

    transpose_to_bf16<<<dim3(32, 32, 4), dim3(32, 8), 0, stream>>>(
        Wq, Wk, Wv, Wo, WqT, WkT, WvT, WoT);

    const int M = BATCH * T_SEQ;
    dim3 gqk(C_DIM / 128, M / 64, 2);
    dim3 g1(C_DIM / 128, M / 64, 1);
    // fused q & k projections (z selects pointer set)
    gemm_bt<true, 0><<<gqk, 256, 0, stream>>>(q, k, WqT, WkT, bq, bk,
                                              qp, kp, M, C_DIM, C_DIM);
    // vp = kp @ Wv -> V^T layout
    gemm_bt<false, 2><<<g1, 256, 0, stream>>>(kp, kp, WvT, WvT, bv, bv,
                                              vt, vt, M, C_DIM, C_DIM);

    attn_kernel<<<dim3(4096), 512, 0, stream>>>(qp, kp, vt, ctx, attn);

    // out = ctx @ Wo (f32)
    gemm_bt<false, 1><<<g1, 256, 0, stream>>>(ctx, ctx, WoT, WoT, bo, bo,
                                              out, out, M, C_DIM, C_DIM);
}

// Round 11
// 250.215 us; speedup vs baseline: 1.0580x; 1.0580x over previous
//
#include <hip/hip_runtime.h>

typedef __attribute__((ext_vector_type(8))) short bf16x8;
typedef __attribute__((ext_vector_type(4))) float f32x4;
typedef unsigned short u16;
typedef unsigned int u32;

#define T_SEQ 2048
#define C_DIM 1024
#define NH 16
#define HD 64
#define BATCH 2

__device__ __forceinline__ u16 f2bf(float f) {
    union { float f; u32 u; } v; v.f = f;
    u32 u = v.u;
    u32 r = (u + 0x7FFFu + ((u >> 16) & 1u)) >> 16;
    return (u16)r;
}

__device__ __forceinline__ float fexp2(float x) { return __builtin_amdgcn_exp2f(x); }

__device__ __forceinline__ float bflo(u32 u) {   // low bf16 -> f32
    union { u32 u; float f; } v; v.u = u << 16; return v.f;
}
__device__ __forceinline__ float bfhi(u32 u) {   // high bf16 -> f32
    union { u32 u; float f; } v; v.u = u & 0xFFFF0000u; return v.f;
}

// async global->LDS, 16B per lane; LDS dest is wave-uniform base + lane*16
__device__ __forceinline__ void gld_lds16(const void* g, void* l) {
    __builtin_amdgcn_global_load_lds(
        (const __attribute__((address_space(1))) void*)g,
        (__attribute__((address_space(3))) void*)l, 16, 0, 0);
}

// ---------------------------------------------------------------------------
// Transpose 4 weight matrices [C,C] f32 -> [C,C] bf16 (WT[n][k] = W[k][n])
// ---------------------------------------------------------------------------
__global__ __launch_bounds__(256) void transpose_to_bf16(
    const float* __restrict__ W0, const float* __restrict__ W1,
    const float* __restrict__ W2, const float* __restrict__ W3,
    u16* __restrict__ O0, u16* __restrict__ O1,
    u16* __restrict__ O2, u16* __restrict__ O3)
{
    __shared__ float tile[32][33];
    const float* W = blockIdx.z == 0 ? W0 : blockIdx.z == 1 ? W1 : blockIdx.z == 2 ? W2 : W3;
    u16* O = blockIdx.z == 0 ? O0 : blockIdx.z == 1 ? O1 : blockIdx.z == 2 ? O2 : O3;
    const int tx = threadIdx.x, ty = threadIdx.y;
    const int bx = blockIdx.x * 32, by = blockIdx.y * 32;
#pragma unroll
    for (int i = 0; i < 4; ++i)
        tile[ty + i * 8][tx] = W[(size_t)(by + ty + i * 8) * C_DIM + bx + tx];
    __syncthreads();
#pragma unroll
    for (int i = 0; i < 4; ++i)
        O[(size_t)(bx + ty + i * 8) * C_DIM + by + tx] = f2bf(tile[tx][ty + i * 8]);
}

// ---------------------------------------------------------------------------
// GEMM (round-9 version, reverted): Y = X @ W + bias, WT[N,K] bf16.
// 64x128 (MxN) tile, BK=32, 4 waves (each 64 rows x 32 cols, acc 4x2).
// Grid (N/128, M/64, nz); blockIdx.z selects pointer set (q/k fusion).
// OMODE: 0 = bf16 row-major, 1 = f32 row-major, 2 = bf16 per-head V^T
// ---------------------------------------------------------------------------
template<bool XF32, int OMODE>
__global__ __launch_bounds__(256) void gemm_bt(
    const void* __restrict__ X0_, const void* __restrict__ X1_,
    const u16* __restrict__ W0T, const u16* __restrict__ W1T,
    const float* __restrict__ b0_, const float* __restrict__ b1_,
    void* __restrict__ Y0_, void* __restrict__ Y1_,
    int M, int N, int K)
{
    __shared__ u16 As[64 * 32];
    __shared__ u16 Bs[128 * 32];
    const int tid = threadIdx.x;
    const int w = tid >> 6, l = tid & 63;
    const int lr = l & 15, lg = l >> 4;
    const int z = blockIdx.z;
    const void* Xv = z ? X1_ : X0_;
    const u16* WT = z ? W1T : W0T;
    const float* bias = z ? b1_ : b0_;
    void* Yv = z ? Y1_ : Y0_;
    const int m0 = blockIdx.y * 64, n0 = blockIdx.x * 128;
    const int grow = l >> 2, gcol = (l & 3) * 8;
    f32x4 acc[4][2] = {};

    for (int k0 = 0; k0 < K; k0 += 32) {
        __syncthreads();
        if (XF32) {
            const int row = tid >> 2, cg = tid & 3;
            const float* g = (const float*)Xv + (size_t)(m0 + row) * K + k0 + cg * 8;
            float4 a0 = *(const float4*)g;
            float4 a1 = *(const float4*)(g + 4);
            union { u16 h[8]; uint4 q; } pk;
            pk.h[0] = f2bf(a0.x); pk.h[1] = f2bf(a0.y);
            pk.h[2] = f2bf(a0.z); pk.h[3] = f2bf(a0.w);
            pk.h[4] = f2bf(a1.x); pk.h[5] = f2bf(a1.y);
            pk.h[6] = f2bf(a1.z); pk.h[7] = f2bf(a1.w);
            *(uint4*)&As[row * 32 + cg * 8] = pk.q;
        } else {
            gld_lds16((const u16*)Xv + (size_t)(m0 + w * 16 + grow) * K + k0 + gcol,
                      &As[w * 512]);
        }
#pragma unroll
        for (int i = 0; i < 2; ++i)
            gld_lds16(WT + (size_t)(n0 + w * 32 + i * 16 + grow) * K + k0 + gcol,
                      &Bs[(w * 2 + i) * 512]);
        __syncthreads();
        bf16x8 af[4], bfr[2];
#pragma unroll
        for (int i = 0; i < 4; ++i)
            af[i] = *(const bf16x8*)&As[(i * 16 + lr) * 32 + lg * 8];
#pragma unroll
        for (int j = 0; j < 2; ++j)
            bfr[j] = *(const bf16x8*)&Bs[(w * 32 + j * 16 + lr) * 32 + lg * 8];
#pragma unroll
        for (int i = 0; i < 4; ++i)
#pragma unroll
            for (int j = 0; j < 2; ++j)
                acc[i][j] = __builtin_amdgcn_mfma_f32_16x16x32_bf16(af[i], bfr[j], acc[i][j], 0, 0, 0);
    }

#pragma unroll
    for (int i = 0; i < 4; ++i) {
        const int rowb = m0 + i * 16 + lg * 4;
#pragma unroll
        for (int j = 0; j < 2; ++j) {
            const int col = n0 + w * 32 + j * 16 + lr;
            const float bv = bias[col];
            if (OMODE == 2) {
                union { u16 h[4]; uint2 q; } pk;
#pragma unroll
                for (int r = 0; r < 4; ++r) pk.h[r] = f2bf(acc[i][j][r] + bv);
                const int bb = rowb >> 11, tt = rowb & 2047;
                const int hh = col >> 6, dd = col & 63;
                u16* dst = (u16*)Yv + ((size_t)((bb * NH + hh) * HD + dd)) * T_SEQ + tt;
                *(uint2*)dst = pk.q;
            } else {
#pragma unroll
                for (int r = 0; r < 4; ++r) {
                    const float v = acc[i][j][r] + bv;
                    if (OMODE == 1)
                        ((float*)Yv)[(size_t)(rowb + r) * N + col] = v;
                    else
                        ((u16*)Yv)[(size_t)(rowb + r) * N + col] = f2bf(v);
                }
            }
        }
    }
}

// ---------------------------------------------------------------------------
// Causal attention. Block = (b, h, 16 q-rows), 8 waves (512 thr), 2 blocks/CU.
// Wave w owns CONSECUTIVE 32-kv tiles [w*nt/8, (w+1)*nt/8).
// Phase 0: zero-fill upper region. Phase A: S once; cache per-tile (mt, S,
// e packed 2xbf16). Phase B: per 2-tile chunk, P written to LDS [16][68] f32
// then stored COALESCED (256B runs, nontemporal); PV MFMA from register
// shuffle-transpose; setprio around MFMA.
// ---------------------------------------------------------------------------
#define PV_QS 67                 // float stride per q-row in pvbuf
#define PV_WS (16 * PV_QS + 8)   // float stride per wave block

__global__ __launch_bounds__(512, 4) void attn_kernel(
    const u16* __restrict__ qp, const u16* __restrict__ kp,
    const u16* __restrict__ vt, u16* __restrict__ ctx,
    float* __restrict__ attn)
{
    __shared__ float statm[8][16], statl[8][16];
    __shared__ float pvbuf[8 * PV_WS];       // 34.6 KB
    __shared__ float pchunk[8][16][68];      // 34.8 KB  (stride 68: conflict-free)

    const int tid = threadIdx.x;
    const int w = tid >> 6, l = tid & 63;
    const int lr = l & 15, lg = l >> 4;

    // XCD-aware bijective swizzle: 4096 blocks, 8 XCDs, 512 blocks each.
    const int wgid = (blockIdx.x & 7) * 512 + (blockIdx.x >> 3);
    const int b = wgid >> 11;
    const int h = (wgid >> 7) & 15;
    const int strip = 127 - (wgid & 127);   // heavy-first within XCD chunk
    const int q0 = strip * 16;

    const size_t bh_off = (size_t)b * T_SEQ * C_DIM + h * HD;
    const u16* qb = qp + bh_off;
    const u16* kb = kp + bh_off;
    const u16* vtb = vt + ((size_t)(b * NH + h) * HD) * T_SEQ;
    float* ab = attn + (size_t)(b * NH + h) * T_SEQ * T_SEQ;

    const float SC = 0.125f * 1.44269504088896f;   // 1/sqrt(64) * log2(e)
    const float MNEG = -1e30f;

    const int qrow = q0 + lr;
    const int nt = (q0 + 47) >> 5;        // 32-wide kv tiles (kv_end = q0+16)
    const int lo = (w * nt) >> 3;         // consecutive-tile split
    const int hi = ((w + 1) * nt) >> 3;

    // ---- phase 0: zero-fill upper region (independent, overlaps A) ----
    {
        const int zs = nt * 32;
        const int row = tid >> 5;           // 0..15
        const int c0 = (tid & 31) * 4;
        float* zr = ab + (size_t)(q0 + row) * T_SEQ;
        const f32x4 z4 = { 0.f, 0.f, 0.f, 0.f };
        for (int c = zs + c0; c < T_SEQ; c += 128)
            __builtin_nontemporal_store(z4, (f32x4*)(zr + c));
    }

    const bf16x8 aq0 = *(const bf16x8*)(qb + (size_t)(q0 + lr) * C_DIM + lg * 8);
    const bf16x8 aq1 = *(const bf16x8*)(qb + (size_t)(q0 + lr) * C_DIM + 32 + lg * 8);

    // ---- phase A: S once; cache mt_j, S_j, packed e per tile ----
    u32 ec[8][2];     // e packed 2xbf16: [jj][t2] r0,r1
    u32 ec2[8][2];    // [jj][t2] r2,r3
    float mtj[8], Sj[8];
    float ml = MNEG;
#pragma unroll
    for (int jj = 0; jj < 8; ++jj) {
        const int ti = lo + jj;
        if (ti < hi) {
            const int kvb = ti * 32;
            const u16* kr0 = kb + (size_t)(kvb + lr) * C_DIM;
            const u16* kr1 = kb + (size_t)(kvb + 16 + lr) * C_DIM;
            const bf16x8 k00 = *(const bf16x8*)(kr0 + lg * 8);
            const bf16x8 k01 = *(const bf16x8*)(kr0 + 32 + lg * 8);
            const bf16x8 k10 = *(const bf16x8*)(kr1 + lg * 8);
            const bf16x8 k11 = *(const bf16x8*)(kr1 + 32 + lg * 8);
            f32x4 s[2] = {};
            s[0] = __builtin_amdgcn_mfma_f32_16x16x32_bf16(k00, aq0, s[0], 0, 0, 0);
            s[0] = __builtin_amdgcn_mfma_f32_16x16x32_bf16(k01, aq1, s[0], 0, 0, 0);
            s[1] = __builtin_amdgcn_mfma_f32_16x16x32_bf16(k10, aq0, s[1], 0, 0, 0);
            s[1] = __builtin_amdgcn_mfma_f32_16x16x32_bf16(k11, aq1, s[1], 0, 0, 0);
            float sv[2][4];
            float mt = MNEG;
#pragma unroll
            for (int t = 0; t < 2; ++t)
#pragma unroll
                for (int r = 0; r < 4; ++r) {
                    float v = s[t][r] * SC;
                    if (kvb + 16 * t + 4 * lg + r > qrow) v = MNEG;
                    sv[t][r] = v;
                    mt = fmaxf(mt, v);
                }
            mtj[jj] = mt;
            float ss = 0.f;
            float e[2][4];
#pragma unroll
            for (int t = 0; t < 2; ++t)
#pragma unroll
                for (int r = 0; r < 4; ++r) {
                    e[t][r] = fexp2(sv[t][r] - mt);
                    ss += e[t][r];
                }
            Sj[jj] = ss;
#pragma unroll
            for (int t = 0; t < 2; ++t) {
                ec[jj][t]  = (u32)f2bf(e[t][0]) | ((u32)f2bf(e[t][1]) << 16);
                ec2[jj][t] = (u32)f2bf(e[t][2]) | ((u32)f2bf(e[t][3]) << 16);
            }
            ml = fmaxf(ml, mt);
        } else {
            mtj[jj] = MNEG; Sj[jj] = 0.f;
            ec[jj][0] = ec[jj][1] = ec2[jj][0] = ec2[jj][1] = 0;
        }
    }
    float ll = 0.f;
#pragma unroll
    for (int jj = 0; jj < 8; ++jj) ll += Sj[jj] * fexp2(mtj[jj] - ml);
    // cross-lane (lg) combine
#pragma unroll
    for (int d = 16; d <= 32; d <<= 1) {
        const float mo = __shfl_xor(ml, d);
        const float lo2 = __shfl_xor(ll, d);
        const float mn = fmaxf(ml, mo);
        ll = ll * fexp2(ml - mn) + lo2 * fexp2(mo - mn);
        ml = mn;
    }
    if (l < 16) { statm[w][lr] = ml; statl[w][lr] = ll; }
    __syncthreads();

    float mf = MNEG;
#pragma unroll
    for (int ww = 0; ww < 8; ++ww) mf = fmaxf(mf, statm[ww][lr]);
    float lf = 0.f;
#pragma unroll
    for (int ww = 0; ww < 8; ++ww) lf += statl[ww][lr] * fexp2(statm[ww][lr] - mf);
    const float rlf = 1.f / lf;

    // ---- phase B: PV + coalesced P stores via per-wave LDS chunks ----
    f32x4 cacc[4] = {};
#pragma unroll
    for (int j0 = 0; j0 < 8; j0 += 2) {
        int nv = 0;
#pragma unroll
        for (int c = 0; c < 2; ++c) {
            const int jj = j0 + c;
            const int ti = lo + jj;
            if (ti < hi) {
                nv = c + 1;
                const int kvb = ti * 32;
                bf16x8 vf[4];
#pragma unroll
                for (int dt = 0; dt < 4; ++dt)
                    vf[dt] = *(const bf16x8*)(vtb + (size_t)(dt * 16 + lr) * T_SEQ + kvb + lg * 8);
                const float scale = fexp2(mtj[jj] - mf) * rlf;
                u32 pw[2][2];
#pragma unroll
                for (int t2 = 0; t2 < 2; ++t2) {
                    float p[4];
                    p[0] = bflo(ec[jj][t2]) * scale;
                    p[1] = bfhi(ec[jj][t2]) * scale;
                    p[2] = bflo(ec2[jj][t2]) * scale;
                    p[3] = bfhi(ec2[jj][t2]) * scale;
                    f32x4 pv4 = { p[0], p[1], p[2], p[3] };
                    *(f32x4*)&pchunk[w][lr][c * 32 + 16 * t2 + 4 * lg] = pv4;
                    pw[t2][0] = (u32)f2bf(p[0]) | ((u32)f2bf(p[1]) << 16);
                    pw[t2][1] = (u32)f2bf(p[2]) | ((u32)f2bf(p[3]) << 16);
                }
                // shuffle-transpose: C-layout -> A-frag (kv=8*lg+jj)
                const int bl = lr + ((lg & 1) << 5);
                const u32 a0 = (u32)__shfl((int)pw[0][0], bl);
                const u32 a1 = (u32)__shfl((int)pw[0][1], bl);
                const u32 a2 = (u32)__shfl((int)pw[0][0], bl + 16);
                const u32 a3 = (u32)__shfl((int)pw[0][1], bl + 16);
                const u32 b0 = (u32)__shfl((int)pw[1][0], bl);
                const u32 b1 = (u32)__shfl((int)pw[1][1], bl);
                const u32 b2 = (u32)__shfl((int)pw[1][0], bl + 16);
                const u32 b3 = (u32)__shfl((int)pw[1][1], bl + 16);
                const bool hi2 = lg >= 2;
                union { u32 ww[4]; bf16x8 v; } pa;
                pa.ww[0] = hi2 ? b0 : a0;
                pa.ww[1] = hi2 ? b1 : a1;
                pa.ww[2] = hi2 ? b2 : a2;
                pa.ww[3] = hi2 ? b3 : a3;
                __builtin_amdgcn_s_setprio(1);
#pragma unroll
                for (int dt = 0; dt < 4; ++dt)
                    cacc[dt] = __builtin_amdgcn_mfma_f32_16x16x32_bf16(pa.v, vf[dt], cacc[dt], 0, 0, 0);
                __builtin_amdgcn_s_setprio(0);
            }
        }
        if (nv) {
            asm volatile("s_waitcnt lgkmcnt(0)" ::: "memory");
            const int colbase = (lo + j0) * 32;
            if (nv == 2) {
#pragma unroll
                for (int i = 0; i < 4; ++i) {
                    const int row = i * 4 + (l >> 4);
                    const int col = (l & 15) * 4;
                    const f32x4 v = *(const f32x4*)&pchunk[w][row][col];
                    __builtin_nontemporal_store(v,
                        (f32x4*)(ab + (size_t)(q0 + row) * T_SEQ + colbase + col));
                }
            } else {
#pragma unroll
                for (int i = 0; i < 2; ++i) {
                    const int row = i * 8 + (l >> 3);
                    const int col = (l & 7) * 4;
                    const f32x4 v = *(const f32x4*)&pchunk[w][row][col];
                    __builtin_nontemporal_store(v,
                        (f32x4*)(ab + (size_t)(q0 + row) * T_SEQ + colbase + col));
                }
            }
        }
    }

    // dump PV partials (cacc[dt][r] = ctx[q=4*lg+r][d=dt*16+lr])
    {
        float* pwv = pvbuf + w * PV_WS;
#pragma unroll
        for (int dt = 0; dt < 4; ++dt)
#pragma unroll
            for (int r = 0; r < 4; ++r)
                pwv[(4 * lg + r) * PV_QS + dt * 16 + lr] = cacc[dt][r];
    }
    __syncthreads();

    // reduce PV across 8 waves + write ctx (bf16): 1024 elems, 512 thr x 2
    {
        const int qq = tid >> 5;            // 0..15
        const int d0 = (tid & 31) * 2;      // 0..62
        float s0 = 0.f, s1 = 0.f;
#pragma unroll
        for (int ww = 0; ww < 8; ++ww) {
            const float* pwv = pvbuf + ww * PV_WS + qq * PV_QS;
            s0 += pwv[d0];
            s1 += pwv[d0 + 1];
        }
        union { u16 hh[2]; u32 u; } pk;
        pk.hh[0] = f2bf(s0); pk.hh[1] = f2bf(s1);
        u16* cb = ctx + bh_off;
        *(u32*)(cb + (size_t)(q0 + qq) * C_DIM + d0) = pk.u;
    }
}

// ---------------------------------------------------------------------------
extern "C" void kernel_launch(void* const* d_in, const int* in_sizes, int n_in,
                              void* d_out, int out_size, void* d_ws, size_t ws_size,
                              hipStream_t stream)
{
    const float* q  = (const float*)d_in[0];
    const float* k  = (const float*)d_in[1];
    const float* Wq = (const float*)d_in[2];
    const float* bq = (const float*)d_in[3];
    const float* Wk = (const float*)d_in[4];
    const float* bk = (const float*)d_in[5];
    const float* Wv = (const float*)d_in[6];
    const float* bv = (const float*)d_in[7];
    const float* Wo = (const float*)d_in[8];
    const float* bo = (const float*)d_in[9];
    (void)in_sizes; (void)n_in; (void)out_size; (void)ws_size;

    float* out = (float*)d_out;
    float* attn = out + (size_t)BATCH * T_SEQ * C_DIM;

    const size_t MC = (size_t)BATCH * T_SEQ * C_DIM;   // 4,194,304 elems
    u16* qp  = (u16*)d_ws;
    u16* kp  = qp + MC;
    u16* vt  = kp + MC;          // V^T: [B][H][D][T]
    u16* ctx = vt + MC;
    u16* WqT = ctx + MC;
    u16* WkT = WqT + (size_t)C_DIM * C_DIM;
    u16* WvT = WkT + (size_t)C_DIM * C_DIM;
    u16* WoT = WvT + (size_t)C_DIM * C_DIM;

    transpose_to_bf16<<<dim3(32, 32, 4), dim3(32, 8), 0, stream>>>(
        Wq, Wk, Wv, Wo, WqT, WkT, WvT, WoT);

    const int M = BATCH * T_SEQ;
    dim3 gqk(C_DIM / 128, M / 64, 2);
    dim3 g1(C_DIM / 128, M / 64, 1);
    // fused q & k projections (z selects pointer set)
    gemm_bt<true, 0><<<gqk, 256, 0, stream>>>(q, k, WqT, WkT, bq, bk,
                                              qp, kp, M, C_DIM, C_DIM);
    // vp = kp @ Wv -> V^T layout
    gemm_bt<false, 2><<<g1, 256, 0, stream>>>(kp, kp, WvT, WvT, bv, bv,
                                              vt, vt, M, C_DIM, C_DIM);

    attn_kernel<<<dim3(4096), 512, 0, stream>>>(qp, kp, vt, ctx, attn);

    // out = ctx @ Wo (f32)
    gemm_bt<false, 1><<<g1, 256, 0, stream>>>(ctx, ctx, WoT, WoT, bo, bo,
                                              out, out, M, C_DIM, C_DIM);
}